// Round 21
// baseline (194.887 us; speedup 1.0000x reference)
//
#include <hip/hip_runtime.h>
#include <math.h>
#include <stdint.h>

#define NTRAIN 16384
#define DIM 64
#define ODIM 8
#define BATCH 8192
#define LOG2E 1.4426950408889634f

typedef float f32x4 __attribute__((ext_vector_type(4)));
typedef _Float16 f16x8 __attribute__((ext_vector_type(8)));
typedef short short8 __attribute__((ext_vector_type(8)));
typedef unsigned short u16;

// float -> fp16 bits, RNE
static __device__ __forceinline__ u16 f2h(float f) {
  return __builtin_bit_cast(u16, (_Float16)f);
}
static __device__ __forceinline__ float h2f(u16 h) {
  return (float)__builtin_bit_cast(_Float16, h);
}
// float -> bf16 bits, RNE
static __device__ __forceinline__ u16 f2bf(float f) {
  unsigned u = __builtin_bit_cast(unsigned, f);
  u += 0x7FFFu + ((u >> 16) & 1u);
  return (u16)(u >> 16);
}

static __device__ __forceinline__ f32x4 mfma_h32(f16x8 a, f16x8 b, f32x4 c) {
  return __builtin_amdgcn_mfma_f32_16x16x32_f16(a, b, c, 0, 0, 0);
}
static __device__ __forceinline__ f32x4 mfma_bf32(short8 a, short8 b, f32x4 c) {
  return __builtin_amdgcn_mfma_f32_16x16x32_bf16(a, b, c, 0, 0, 0);
}
// 2^(-x)
static __device__ __forceinline__ float ex2n(float x) {
  float r;
  asm("v_exp_f32 %0, -%1" : "=v"(r) : "v"(x));
  return r;
}
// pack two f32 -> one u32 of 2 bf16 (keeps fp32 exponent range)
static __device__ __forceinline__ unsigned pkbf(float a, float b) {
  unsigned d;
  asm("v_cvt_pk_bf16_f32 %0, %1, %2" : "=v"(d) : "v"(a), "v"(b));
  return d;
}

// ---------------------------------------------------------------------------
// k_frag: zeroes the completion flags, builds X fragments (one wave per 16-n
// tile, xt read once, norms via shfl) and V pair fragments (bf16).
// ---------------------------------------------------------------------------
__global__ __launch_bounds__(256) void k_frag(
    const float* __restrict__ xt, const float* __restrict__ yt,
    const float* __restrict__ beta,
    u16* __restrict__ xf, u16* __restrict__ yv, int* __restrict__ flags) {
  int tid = blockIdx.x * 256 + threadIdx.x;
  if (tid < 64) flags[tid] = 0;  // completion flags for the fused reduction

  if (tid < (NTRAIN / 16) * 64) {  // X fragments: 1 wave per tile
    int tile = tid >> 6, lane = tid & 63;
    int lr = lane & 15, lg = lane >> 4;
    int n = tile * 16 + lr;
    float g = beta[n] * LOG2E;
    float g2v = g * g;
    float s2g = 2.0f * g2v;
    const float* row = xt + (size_t)n * DIM;
    float4 a0 = *(const float4*)(row + lg * 8);
    float4 a1 = *(const float4*)(row + lg * 8 + 4);
    float4 b0 = *(const float4*)(row + 32 + lg * 8);
    float4 b1 = *(const float4*)(row + 32 + lg * 8 + 4);
    float ssq = 0.f;
    ssq = fmaf(a0.x, a0.x, ssq); ssq = fmaf(a0.y, a0.y, ssq);
    ssq = fmaf(a0.z, a0.z, ssq); ssq = fmaf(a0.w, a0.w, ssq);
    ssq = fmaf(a1.x, a1.x, ssq); ssq = fmaf(a1.y, a1.y, ssq);
    ssq = fmaf(a1.z, a1.z, ssq); ssq = fmaf(a1.w, a1.w, ssq);
    ssq = fmaf(b0.x, b0.x, ssq); ssq = fmaf(b0.y, b0.y, ssq);
    ssq = fmaf(b0.z, b0.z, ssq); ssq = fmaf(b0.w, b0.w, ssq);
    ssq = fmaf(b1.x, b1.x, ssq); ssq = fmaf(b1.y, b1.y, ssq);
    ssq = fmaf(b1.z, b1.z, ssq); ssq = fmaf(b1.w, b1.w, ssq);
    ssq += __shfl_xor(ssq, 16);
    ssq += __shfl_xor(ssq, 32);

    uint4 u0, u1;
    {
      unsigned e[8];
      float v[8] = {a0.x, a0.y, a0.z, a0.w, a1.x, a1.y, a1.z, a1.w};
#pragma unroll
      for (int j = 0; j < 8; ++j) e[j] = f2h(s2g * v[j]);
      u0.x = e[0] | (e[1] << 16); u0.y = e[2] | (e[3] << 16);
      u0.z = e[4] | (e[5] << 16); u0.w = e[6] | (e[7] << 16);
    }
    {
      unsigned e[8];
      float v[8] = {b0.x, b0.y, b0.z, b0.w, b1.x, b1.y, b1.z, b1.w};
#pragma unroll
      for (int j = 0; j < 8; ++j) e[j] = f2h(s2g * v[j]);
      u1.x = e[0] | (e[1] << 16); u1.y = e[2] | (e[3] << 16);
      u1.z = e[4] | (e[5] << 16); u1.w = e[6] | (e[7] << 16);
    }
    uint4 u2 = {0, 0, 0, 0};
    if (lg == 0) {
      float gx2v = g2v * ssq;
      u16 xh = f2h(gx2v);
      u16 xl = f2h(gx2v - h2f(xh));
      u16 gh = f2h(g2v);
      u16 gl = f2h(g2v - h2f(gh));
      u2.x = (unsigned)xh | ((unsigned)xl << 16);
      u2.y = (unsigned)gh | ((unsigned)gh << 16);
      u2.z = (unsigned)gl;
    }
    uint4* dst = (uint4*)xf + (size_t)tile * 3 * 64;
    dst[0 * 64 + lane] = u0;
    dst[1 * 64 + lane] = u1;
    dst[2 * 64 + lane] = u2;
    return;
  }
  tid -= (NTRAIN / 16) * 64;

  if (tid < (NTRAIN / 32) * 64) {  // V pair fragments (bf16)
    int t = tid >> 6, lane = tid & 63;
    int col = lane & 15, lg = lane >> 4;
    unsigned e[8];
#pragma unroll
    for (int j = 0; j < 8; ++j) {
      int n = t * 32 + ((j < 4) ? (lg * 4 + j) : (16 + lg * 4 + (j - 4)));
      float v = (col == 0) ? 1.0f
                           : ((col < 9) ? yt[(size_t)n * ODIM + (col - 1)] : 0.0f);
      e[j] = f2bf(v);
    }
    uint4 u;
    u.x = e[0] | (e[1] << 16); u.y = e[2] | (e[3] << 16);
    u.z = e[4] | (e[5] << 16); u.w = e[6] | (e[7] << 16);
    ((uint4*)yv)[(size_t)t * 64 + lane] = u;
  }
}

// ---------------------------------------------------------------------------
// Pass 1 (fused): wave = 64 m-rows (4 x 16 tiles), fp16 S (3 MFMAs incl
// norm-fold), bf16 P, one 16x16x32 bf16 PV per 2 slabs per tile. No setprio
// (it deprioritized other waves' trans issue - our bottleneck pipe).
// The LAST block per m-tile (device-scope atomic flag) reduces all chunks in
// fixed order (deterministic) and writes the final output - pass2 eliminated.
// ---------------------------------------------------------------------------
#define LOADX3(X_, nbv)                                                       \
  {                                                                           \
    const size_t fb_ = (size_t)((nbv) >> 4) * 3;                              \
    X_[0] = xf4[(fb_ + 0) * 64 + lane];                                       \
    X_[1] = xf4[(fb_ + 1) * 64 + lane];                                       \
    X_[2] = xf4[(fb_ + 2) * 64 + lane];                                       \
  }

#define SCOMP(X_, t_, U0_, U1_)                                               \
  {                                                                           \
    f32x4 sA = {0.f, 0.f, 0.f, 0.f};                                          \
    sA = mfma_h32(__builtin_bit_cast(f16x8, X_[2]), BN[t_], sA);              \
    sA = mfma_h32(__builtin_bit_cast(f16x8, X_[0]), BH[t_][0], sA);           \
    sA = mfma_h32(__builtin_bit_cast(f16x8, X_[1]), BH[t_][1], sA);           \
    float w0 = ex2n(__builtin_amdgcn_sqrtf(fabsf(sA[0])));                    \
    float w1 = ex2n(__builtin_amdgcn_sqrtf(fabsf(sA[1])));                    \
    float w2 = ex2n(__builtin_amdgcn_sqrtf(fabsf(sA[2])));                    \
    float w3 = ex2n(__builtin_amdgcn_sqrtf(fabsf(sA[3])));                    \
    U0_ = pkbf(w0, w1);                                                       \
    U1_ = pkbf(w2, w3);                                                       \
  }

__global__ __launch_bounds__(256, 4) void grnn_pass1(
    const u16* __restrict__ xf, const u16* __restrict__ yv,
    const float* __restrict__ batches,
    float* __restrict__ partial, int* __restrict__ flags,
    float* __restrict__ out, int chunk_n, int nc) {
  __shared__ int is_last;
  const int lane = threadIdx.x & 63;
  const int lr = lane & 15, lg = lane >> 4;

  // XCD c-locality swizzle (bijective for nc==32, grid 1024 = 8*4*32).
  int mt, c;
  if (nc == 32) {
    const int bid = blockIdx.x;
    const int xcd = bid & 7;
    const int q = bid >> 3;          // 0..127
    c = xcd + 8 * (q & 3);           // 4 c-slices per XCD
    mt = q >> 2;                     // 0..31
  } else {
    mt = blockIdx.x % (BATCH / 256);
    c = blockIdx.x / (BATCH / 256);
  }
  const int mbase = mt * 256 + (threadIdx.x >> 6) * 64;  // wave's 64 m-rows
  const int n0 = c * chunk_n;
  const int npair = chunk_n / 32;

  // Batch fragments for 4 m-tiles; b2 via in-wave shfl reduce.
  f16x8 BH[4][2], BN[4];
  f32x4 pv[4];
#pragma unroll
  for (int t = 0; t < 4; ++t) {
    const int mrow = mbase + t * 16 + lr;
    float ssum = 0.f;
#pragma unroll
    for (int ks = 0; ks < 2; ++ks) {
      const float* src = batches + (size_t)mrow * DIM + ks * 32 + lg * 8;
      float4 v0 = *(const float4*)src;
      float4 v1 = *(const float4*)(src + 4);
      BH[t][ks][0] = (_Float16)v0.x; BH[t][ks][1] = (_Float16)v0.y;
      BH[t][ks][2] = (_Float16)v0.z; BH[t][ks][3] = (_Float16)v0.w;
      BH[t][ks][4] = (_Float16)v1.x; BH[t][ks][5] = (_Float16)v1.y;
      BH[t][ks][6] = (_Float16)v1.z; BH[t][ks][7] = (_Float16)v1.w;
      ssum = fmaf(v0.x, v0.x, ssum); ssum = fmaf(v0.y, v0.y, ssum);
      ssum = fmaf(v0.z, v0.z, ssum); ssum = fmaf(v0.w, v0.w, ssum);
      ssum = fmaf(v1.x, v1.x, ssum); ssum = fmaf(v1.y, v1.y, ssum);
      ssum = fmaf(v1.z, v1.z, ssum); ssum = fmaf(v1.w, v1.w, ssum);
    }
    ssum += __shfl_xor(ssum, 16);
    ssum += __shfl_xor(ssum, 32);
#pragma unroll
    for (int j = 0; j < 8; ++j) BN[t][j] = (_Float16)0.0f;
    if (lg == 0) {
      _Float16 bh = (_Float16)ssum;
      _Float16 bl = (_Float16)(ssum - (float)bh);
      BN[t][0] = (_Float16)(-1.0f);
      BN[t][1] = (_Float16)(-1.0f);
      BN[t][2] = -bh;
      BN[t][3] = -bl;
      BN[t][4] = -bh;
    }
    pv[t] = (f32x4){0.f, 0.f, 0.f, 0.f};
  }

  const uint4* xf4 = (const uint4*)xf;
  const uint4* yv4 = (const uint4*)yv;

  uint4 Xa[3], Xb[3], Vp, Vn;
  LOADX3(Xa, n0)
  LOADX3(Xb, n0 + 16)
  Vp = yv4[(size_t)(n0 >> 5) * 64 + lane];

  for (int p = 0; p < npair; ++p) {
    const int nb = n0 + p * 32;
    unsigned A0[4], A1[4], B0[4], B1[4];
#pragma unroll
    for (int t = 0; t < 4; ++t) SCOMP(Xa, t, A0[t], A1[t])
    if (p + 1 < npair) LOADX3(Xa, nb + 32)
#pragma unroll
    for (int t = 0; t < 4; ++t) SCOMP(Xb, t, B0[t], B1[t])
    if (p + 1 < npair) {
      LOADX3(Xb, nb + 48)
      Vn = yv4[(size_t)((nb + 32) >> 5) * 64 + lane];
    }
#pragma unroll
    for (int t = 0; t < 4; ++t) {
      uint4 pa = {A0[t], A1[t], B0[t], B1[t]};
      pv[t] = mfma_bf32(__builtin_bit_cast(short8, pa),
                        __builtin_bit_cast(short8, Vp), pv[t]);
    }
    Vp = Vn;
  }

  // Epilogue: partial[c][col][m]; col 0 = sum(w), 1..8 = sum(w*y).
  float* pc = partial + (size_t)c * 9 * BATCH;
  if (lr < 9) {
#pragma unroll
    for (int t = 0; t < 4; ++t)
#pragma unroll
      for (int r = 0; r < 4; ++r)
        pc[(size_t)lr * BATCH + (mbase + t * 16 + lg * 4 + r)] = pv[t][r];
  }

  // Fused reduction: last block for this m-tile sums all chunks (fixed
  // order -> deterministic) and writes the output.
  __threadfence();
  if (threadIdx.x == 0) {
    int old = atomicAdd(&flags[mt], 1);
    is_last = (old == nc - 1) ? 1 : 0;
  }
  __syncthreads();
  if (is_last) {
    __threadfence();
    const int b = mt * 256 + threadIdx.x;  // this block's 256 m-rows
    float s[9];
#pragma unroll
    for (int j = 0; j < 9; ++j) s[j] = 0.f;
    for (int cc = 0; cc < nc; ++cc) {
      const float* p = partial + (size_t)cc * 9 * BATCH;
#pragma unroll
      for (int j = 0; j < 9; ++j) s[j] += p[(size_t)j * BATCH + b];
    }
    const float inv = 1.f / s[0];
#pragma unroll
    for (int j = 0; j < ODIM; ++j) out[(size_t)b * ODIM + j] = s[j + 1] * inv;
  }
}

// ---------------------------------------------------------------------------
extern "C" void kernel_launch(void* const* d_in, const int* in_sizes, int n_in,
                              void* d_out, int out_size, void* d_ws, size_t ws_size,
                              hipStream_t stream) {
  const float* batches = (const float*)d_in[0];  // [8192, 64]
  const float* xt      = (const float*)d_in[1];  // [16384, 64]
  const float* yt      = (const float*)d_in[2];  // [16384, 8]
  const float* beta    = (const float*)d_in[3];  // [1, 16384]
  float* out = (float*)d_out;                    // [8192, 8]

  const size_t xf_b = (size_t)(NTRAIN / 16) * 3 * 1024;    // 3 MB
  const size_t yv_b = (size_t)(NTRAIN / 32) * 64 * 16;     // 512 KB
  const size_t fl_b = 64 * sizeof(int);
  const size_t fixed = xf_b + yv_b + fl_b;
  const size_t per_chunk = (size_t)9 * BATCH * 4;          // 288 KB

  int nc = 32;
  while (nc > 1 && fixed + (size_t)nc * per_chunk > ws_size) nc >>= 1;
  const int chunk_n = NTRAIN / nc;

  char* p = (char*)d_ws;
  u16* xf = (u16*)p;      p += xf_b;
  u16* yv = (u16*)p;      p += yv_b;
  int* flags = (int*)p;   p += fl_b;
  float* partial = (float*)p;

  const int frag_threads = (NTRAIN / 16) * 64 + (NTRAIN / 32) * 64;
  k_frag<<<(frag_threads + 255) / 256, 256, 0, stream>>>(
      xt, yt, beta, xf, yv, flags);
  grnn_pass1<<<(BATCH / 256) * nc, 256, 0, stream>>>(
      xf, yv, batches, partial, flags, out, chunk_n, nc);
}

// Round 22
// 66.159 us; speedup vs baseline: 2.9457x; 2.9457x over previous
//
#include <hip/hip_runtime.h>
#include <math.h>
#include <stdint.h>

#define NTRAIN 16384
#define DIM 64
#define ODIM 8
#define BATCH 8192
#define LOG2E 1.4426950408889634f

typedef float f32x4 __attribute__((ext_vector_type(4)));
typedef _Float16 f16x8 __attribute__((ext_vector_type(8)));
typedef short short8 __attribute__((ext_vector_type(8)));
typedef unsigned short u16;

// float -> fp16 bits, RNE
static __device__ __forceinline__ u16 f2h(float f) {
  return __builtin_bit_cast(u16, (_Float16)f);
}
static __device__ __forceinline__ float h2f(u16 h) {
  return (float)__builtin_bit_cast(_Float16, h);
}
// float -> bf16 bits, RNE
static __device__ __forceinline__ u16 f2bf(float f) {
  unsigned u = __builtin_bit_cast(unsigned, f);
  u += 0x7FFFu + ((u >> 16) & 1u);
  return (u16)(u >> 16);
}

static __device__ __forceinline__ f32x4 mfma_h32(f16x8 a, f16x8 b, f32x4 c) {
  return __builtin_amdgcn_mfma_f32_16x16x32_f16(a, b, c, 0, 0, 0);
}
static __device__ __forceinline__ f32x4 mfma_bf32(short8 a, short8 b, f32x4 c) {
  return __builtin_amdgcn_mfma_f32_16x16x32_bf16(a, b, c, 0, 0, 0);
}
// 2^(-x)
static __device__ __forceinline__ float ex2n(float x) {
  float r;
  asm("v_exp_f32 %0, -%1" : "=v"(r) : "v"(x));
  return r;
}
// pack two f32 -> one u32 of 2 bf16 (keeps fp32 exponent range)
static __device__ __forceinline__ unsigned pkbf(float a, float b) {
  unsigned d;
  asm("v_cvt_pk_bf16_f32 %0, %1, %2" : "=v"(d) : "v"(a), "v"(b));
  return d;
}

// ---------------------------------------------------------------------------
// k_frag: one wave per 16-n X tile (xt read once, norms via shfl) + V pair
// fragments (bf16; slab A k-slots 0..3, slab B 4..7).
// ---------------------------------------------------------------------------
__global__ __launch_bounds__(256) void k_frag(
    const float* __restrict__ xt, const float* __restrict__ yt,
    const float* __restrict__ beta,
    u16* __restrict__ xf, u16* __restrict__ yv) {
  int tid = blockIdx.x * 256 + threadIdx.x;

  if (tid < (NTRAIN / 16) * 64) {  // X fragments: 1 wave per tile
    int tile = tid >> 6, lane = tid & 63;
    int lr = lane & 15, lg = lane >> 4;
    int n = tile * 16 + lr;
    float g = beta[n] * LOG2E;
    float g2v = g * g;
    float s2g = 2.0f * g2v;
    const float* row = xt + (size_t)n * DIM;
    float4 a0 = *(const float4*)(row + lg * 8);
    float4 a1 = *(const float4*)(row + lg * 8 + 4);
    float4 b0 = *(const float4*)(row + 32 + lg * 8);
    float4 b1 = *(const float4*)(row + 32 + lg * 8 + 4);
    float ssq = 0.f;
    ssq = fmaf(a0.x, a0.x, ssq); ssq = fmaf(a0.y, a0.y, ssq);
    ssq = fmaf(a0.z, a0.z, ssq); ssq = fmaf(a0.w, a0.w, ssq);
    ssq = fmaf(a1.x, a1.x, ssq); ssq = fmaf(a1.y, a1.y, ssq);
    ssq = fmaf(a1.z, a1.z, ssq); ssq = fmaf(a1.w, a1.w, ssq);
    ssq = fmaf(b0.x, b0.x, ssq); ssq = fmaf(b0.y, b0.y, ssq);
    ssq = fmaf(b0.z, b0.z, ssq); ssq = fmaf(b0.w, b0.w, ssq);
    ssq = fmaf(b1.x, b1.x, ssq); ssq = fmaf(b1.y, b1.y, ssq);
    ssq = fmaf(b1.z, b1.z, ssq); ssq = fmaf(b1.w, b1.w, ssq);
    ssq += __shfl_xor(ssq, 16);
    ssq += __shfl_xor(ssq, 32);

    uint4 u0, u1;
    {
      unsigned e[8];
      float v[8] = {a0.x, a0.y, a0.z, a0.w, a1.x, a1.y, a1.z, a1.w};
#pragma unroll
      for (int j = 0; j < 8; ++j) e[j] = f2h(s2g * v[j]);
      u0.x = e[0] | (e[1] << 16); u0.y = e[2] | (e[3] << 16);
      u0.z = e[4] | (e[5] << 16); u0.w = e[6] | (e[7] << 16);
    }
    {
      unsigned e[8];
      float v[8] = {b0.x, b0.y, b0.z, b0.w, b1.x, b1.y, b1.z, b1.w};
#pragma unroll
      for (int j = 0; j < 8; ++j) e[j] = f2h(s2g * v[j]);
      u1.x = e[0] | (e[1] << 16); u1.y = e[2] | (e[3] << 16);
      u1.z = e[4] | (e[5] << 16); u1.w = e[6] | (e[7] << 16);
    }
    uint4 u2 = {0, 0, 0, 0};
    if (lg == 0) {
      float gx2v = g2v * ssq;
      u16 xh = f2h(gx2v);
      u16 xl = f2h(gx2v - h2f(xh));
      u16 gh = f2h(g2v);
      u16 gl = f2h(g2v - h2f(gh));
      u2.x = (unsigned)xh | ((unsigned)xl << 16);
      u2.y = (unsigned)gh | ((unsigned)gh << 16);
      u2.z = (unsigned)gl;
    }
    uint4* dst = (uint4*)xf + (size_t)tile * 3 * 64;
    dst[0 * 64 + lane] = u0;
    dst[1 * 64 + lane] = u1;
    dst[2 * 64 + lane] = u2;
    return;
  }
  tid -= (NTRAIN / 16) * 64;

  if (tid < (NTRAIN / 32) * 64) {  // V pair fragments (bf16)
    int t = tid >> 6, lane = tid & 63;
    int col = lane & 15, lg = lane >> 4;
    unsigned e[8];
#pragma unroll
    for (int j = 0; j < 8; ++j) {
      int n = t * 32 + ((j < 4) ? (lg * 4 + j) : (16 + lg * 4 + (j - 4)));
      float v = (col == 0) ? 1.0f
                           : ((col < 9) ? yt[(size_t)n * ODIM + (col - 1)] : 0.0f);
      e[j] = f2bf(v);
    }
    uint4 u;
    u.x = e[0] | (e[1] << 16); u.y = e[2] | (e[3] << 16);
    u.z = e[4] | (e[5] << 16); u.w = e[6] | (e[7] << 16);
    ((uint4*)yv)[(size_t)t * 64 + lane] = u;
  }
}

// ---------------------------------------------------------------------------
// Pass 1: wave = 64 m-rows (4 x 16 tiles), fp16 S (3 MFMAs incl norm-fold),
// bf16 P, one 16x16x32 bf16 PV per 2 slabs per tile. Barrier-free;
// register-double-buffered; XCD c-locality swizzle. NO setprio (it boosts
// the MFMA cluster at the expense of other waves' trans issue - the
// bottleneck pipe here).
// ---------------------------------------------------------------------------
#define LOADX3(X_, nbv)                                                       \
  {                                                                           \
    const size_t fb_ = (size_t)((nbv) >> 4) * 3;                              \
    X_[0] = xf4[(fb_ + 0) * 64 + lane];                                       \
    X_[1] = xf4[(fb_ + 1) * 64 + lane];                                       \
    X_[2] = xf4[(fb_ + 2) * 64 + lane];                                       \
  }

#define SCOMP(X_, t_, U0_, U1_)                                               \
  {                                                                           \
    f32x4 sA = {0.f, 0.f, 0.f, 0.f};                                          \
    sA = mfma_h32(__builtin_bit_cast(f16x8, X_[2]), BN[t_], sA);              \
    sA = mfma_h32(__builtin_bit_cast(f16x8, X_[0]), BH[t_][0], sA);           \
    sA = mfma_h32(__builtin_bit_cast(f16x8, X_[1]), BH[t_][1], sA);           \
    float w0 = ex2n(__builtin_amdgcn_sqrtf(fabsf(sA[0])));                    \
    float w1 = ex2n(__builtin_amdgcn_sqrtf(fabsf(sA[1])));                    \
    float w2 = ex2n(__builtin_amdgcn_sqrtf(fabsf(sA[2])));                    \
    float w3 = ex2n(__builtin_amdgcn_sqrtf(fabsf(sA[3])));                    \
    U0_ = pkbf(w0, w1);                                                       \
    U1_ = pkbf(w2, w3);                                                       \
  }

__global__ __launch_bounds__(256, 4) void grnn_pass1(
    const u16* __restrict__ xf, const u16* __restrict__ yv,
    const float* __restrict__ batches,
    float* __restrict__ partial, int chunk_n, int nc) {
  const int lane = threadIdx.x & 63;
  const int lr = lane & 15, lg = lane >> 4;

  // XCD c-locality swizzle (bijective for nc==32, grid 1024 = 8*4*32).
  int mt, c;
  if (nc == 32) {
    const int bid = blockIdx.x;
    const int xcd = bid & 7;
    const int q = bid >> 3;          // 0..127
    c = xcd + 8 * (q & 3);           // 4 c-slices per XCD
    mt = q >> 2;                     // 0..31
  } else {
    mt = blockIdx.x % (BATCH / 256);
    c = blockIdx.x / (BATCH / 256);
  }
  const int mbase = mt * 256 + (threadIdx.x >> 6) * 64;  // wave's 64 m-rows
  const int n0 = c * chunk_n;
  const int npair = chunk_n / 32;

  // Batch fragments for 4 m-tiles; b2 via in-wave shfl reduce.
  f16x8 BH[4][2], BN[4];
  f32x4 pv[4];
#pragma unroll
  for (int t = 0; t < 4; ++t) {
    const int mrow = mbase + t * 16 + lr;
    float ssum = 0.f;
#pragma unroll
    for (int ks = 0; ks < 2; ++ks) {
      const float* src = batches + (size_t)mrow * DIM + ks * 32 + lg * 8;
      float4 v0 = *(const float4*)src;
      float4 v1 = *(const float4*)(src + 4);
      BH[t][ks][0] = (_Float16)v0.x; BH[t][ks][1] = (_Float16)v0.y;
      BH[t][ks][2] = (_Float16)v0.z; BH[t][ks][3] = (_Float16)v0.w;
      BH[t][ks][4] = (_Float16)v1.x; BH[t][ks][5] = (_Float16)v1.y;
      BH[t][ks][6] = (_Float16)v1.z; BH[t][ks][7] = (_Float16)v1.w;
      ssum = fmaf(v0.x, v0.x, ssum); ssum = fmaf(v0.y, v0.y, ssum);
      ssum = fmaf(v0.z, v0.z, ssum); ssum = fmaf(v0.w, v0.w, ssum);
      ssum = fmaf(v1.x, v1.x, ssum); ssum = fmaf(v1.y, v1.y, ssum);
      ssum = fmaf(v1.z, v1.z, ssum); ssum = fmaf(v1.w, v1.w, ssum);
    }
    ssum += __shfl_xor(ssum, 16);
    ssum += __shfl_xor(ssum, 32);
#pragma unroll
    for (int j = 0; j < 8; ++j) BN[t][j] = (_Float16)0.0f;
    if (lg == 0) {
      _Float16 bh = (_Float16)ssum;
      _Float16 bl = (_Float16)(ssum - (float)bh);
      BN[t][0] = (_Float16)(-1.0f);
      BN[t][1] = (_Float16)(-1.0f);
      BN[t][2] = -bh;
      BN[t][3] = -bl;
      BN[t][4] = -bh;
    }
    pv[t] = (f32x4){0.f, 0.f, 0.f, 0.f};
  }

  const uint4* xf4 = (const uint4*)xf;
  const uint4* yv4 = (const uint4*)yv;

  uint4 Xa[3], Xb[3], Vp, Vn;
  LOADX3(Xa, n0)
  LOADX3(Xb, n0 + 16)
  Vp = yv4[(size_t)(n0 >> 5) * 64 + lane];

  for (int p = 0; p < npair; ++p) {
    const int nb = n0 + p * 32;
    unsigned A0[4], A1[4], B0[4], B1[4];
#pragma unroll
    for (int t = 0; t < 4; ++t) SCOMP(Xa, t, A0[t], A1[t])
    if (p + 1 < npair) LOADX3(Xa, nb + 32)
#pragma unroll
    for (int t = 0; t < 4; ++t) SCOMP(Xb, t, B0[t], B1[t])
    if (p + 1 < npair) {
      LOADX3(Xb, nb + 48)
      Vn = yv4[(size_t)((nb + 32) >> 5) * 64 + lane];
    }
#pragma unroll
    for (int t = 0; t < 4; ++t) {
      uint4 pa = {A0[t], A1[t], B0[t], B1[t]};
      pv[t] = mfma_bf32(__builtin_bit_cast(short8, pa),
                        __builtin_bit_cast(short8, Vp), pv[t]);
    }
    Vp = Vn;
  }

  // Epilogue: C[row=lg*4+r][col=lr]; col 0 = sum(w), 1..8 = sum(w*y).
  float* pc = partial + (size_t)c * 9 * BATCH;
  if (lr < 9) {
#pragma unroll
    for (int t = 0; t < 4; ++t)
#pragma unroll
      for (int r = 0; r < 4; ++r)
        pc[(size_t)lr * BATCH + (mbase + t * 16 + lg * 4 + r)] = pv[t][r];
  }
}

// ---------------------------------------------------------------------------
// Pass 2: 256 blocks x 64 threads. Thread = (b, chunk-half); shfl_xor(32)
// combines halves; lanes<32 divide + write.
// ---------------------------------------------------------------------------
__global__ __launch_bounds__(64) void grnn_pass2(const float* __restrict__ partial,
                                                 float* __restrict__ out, int nc) {
  const int lane = threadIdx.x & 63;
  const int half = lane >> 5;
  const int b = blockIdx.x * 32 + (lane & 31);
  const int per = nc >> 1;

  float s[9];
#pragma unroll
  for (int j = 0; j < 9; ++j) s[j] = 0.f;
  for (int cc = half * per; cc < half * per + per; ++cc) {
    const float* p = partial + (size_t)cc * 9 * BATCH;
#pragma unroll
    for (int j = 0; j < 9; ++j) s[j] += p[(size_t)j * BATCH + b];
  }
  if ((nc & 1) && half == 0) {
    const float* p = partial + (size_t)(nc - 1) * 9 * BATCH;
#pragma unroll
    for (int j = 0; j < 9; ++j) s[j] += p[(size_t)j * BATCH + b];
  }
#pragma unroll
  for (int j = 0; j < 9; ++j) s[j] += __shfl_xor(s[j], 32);

  if (half == 0) {
    const float inv = 1.f / s[0];
#pragma unroll
    for (int j = 0; j < ODIM; ++j) out[(size_t)b * ODIM + j] = s[j + 1] * inv;
  }
}

// ---------------------------------------------------------------------------
extern "C" void kernel_launch(void* const* d_in, const int* in_sizes, int n_in,
                              void* d_out, int out_size, void* d_ws, size_t ws_size,
                              hipStream_t stream) {
  const float* batches = (const float*)d_in[0];  // [8192, 64]
  const float* xt      = (const float*)d_in[1];  // [16384, 64]
  const float* yt      = (const float*)d_in[2];  // [16384, 8]
  const float* beta    = (const float*)d_in[3];  // [1, 16384]
  float* out = (float*)d_out;                    // [8192, 8]

  const size_t xf_b = (size_t)(NTRAIN / 16) * 3 * 1024;    // 3 MB
  const size_t yv_b = (size_t)(NTRAIN / 32) * 64 * 16;     // 512 KB
  const size_t fixed = xf_b + yv_b;
  const size_t per_chunk = (size_t)9 * BATCH * 4;          // 288 KB

  int nc = 32;
  while (nc > 1 && fixed + (size_t)nc * per_chunk > ws_size) nc >>= 1;
  const int chunk_n = NTRAIN / nc;

  char* p = (char*)d_ws;
  u16* xf = (u16*)p;      p += xf_b;
  u16* yv = (u16*)p;      p += yv_b;
  float* partial = (float*)p;

  const int frag_threads = (NTRAIN / 16) * 64 + (NTRAIN / 32) * 64;
  k_frag<<<(frag_threads + 255) / 256, 256, 0, stream>>>(xt, yt, beta, xf, yv);
  grnn_pass1<<<(BATCH / 256) * nc, 256, 0, stream>>>(
      xf, yv, batches, partial, chunk_n, nc);
  grnn_pass2<<<BATCH / 32, 64, 0, stream>>>(partial, out, nc);
}